// Round 3
// baseline (574.464 us; speedup 1.0000x reference)
//
#include <hip/hip_runtime.h>
#include <stdint.h>

// R3: dtype fix — reference is float32 (setup_inputs uses jnp.float32 throughout).
// All global inputs/outputs are fp32; MFMA core stays bf16 (threshold 4.69e-2 is
// bf16-compute scale). pack_weights converts fp32->bf16 during transpose.
// Staging kept synchronous (from R2) to change one variable at a time.

#define NRAYS 4096

typedef unsigned short u16;
typedef __attribute__((ext_vector_type(8))) short short8;
typedef __attribute__((ext_vector_type(4))) float f32x4;

__device__ __forceinline__ u16 f2bf(float f) {
  union { float f; uint32_t i; } v; v.f = f;
  return (u16)((v.i + 0x7FFFu + ((v.i >> 16) & 1u)) >> 16);
}
__device__ __forceinline__ float bf2f(u16 u) {
  union { uint32_t i; float f; } v; v.i = ((uint32_t)u) << 16; return v.f;
}

// ---------------- weight transpose + fp32->bf16 convert into workspace ----------------
// ws layout (bf16 elems): W2t [256n][256k] @0, W3t [256n][256k] @65536, W4t [128n][256k] @131072
__global__ void pack_weights(const float* __restrict__ W2, const float* __restrict__ W3,
                             const float* __restrict__ W4, u16* __restrict__ ws) {
  int idx = blockIdx.x * 256 + threadIdx.x;   // grid covers exactly 163840
  float v;
  if (idx < 65536) {
    int n = idx >> 8, k = idx & 255;
    v = W2[k * 256 + n];
  } else if (idx < 131072) {
    int o = idx - 65536, n = o >> 8, k = o & 255;
    v = W3[k * 256 + n];
  } else {
    int o = idx - 131072, n = o >> 8, k = o & 255;
    v = W4[k * 128 + n];
  }
  ws[idx] = f2bf(v);
}

// LDS map (bytes)
#define OFF_ACT   0        // 128 x 256 bf16 = 65536
#define OFF_WBUF  65536    // 128 x 256 bf16 = 65536
#define OFF_ZV    131072   // 128 f32
#define OFF_DIST  131584   // 128 f32
#define OFF_DENS  132096   // 128 f32
#define OFF_RGB   132608   // 128 x 4 f32
#define OFF_VDIR  134656   // 8 f32
#define OFF_W5    134688   // 384 f32
#define OFF_B5    136224   // 4 f32
#define LDS_TOTAL 136240

// stage a 64KB [128n][256k] bf16 weight chunk into LDS with slot swizzle u = s ^ (n&31)
__device__ __forceinline__ void stage64k(const u16* __restrict__ src, u16* wbuf, int t) {
  short8 v[8];
#pragma unroll
  for (int g = 0; g < 8; g++) {
    int tt = g * 512 + t;            // destination 16B slot index, 4096 slots
    int n = tt >> 5, u = tt & 31;
    int s = u ^ (n & 31);            // logical k-slot that belongs at physical u
    v[g] = *(const short8*)(src + ((n << 5) + s) * 8);
  }
#pragma unroll
  for (int g = 0; g < 8; g++) {
    int tt = g * 512 + t;
    *(short8*)(wbuf + tt * 8) = v[g];
  }
}

// one K=256 MFMA pass over a staged 128-col chunk; wave tile = 2 row-tiles x 4 col-tiles
__device__ __forceinline__ void kloop(const u16* __restrict__ act, const u16* __restrict__ wbuf,
                                      int rg, int cg, int quad, int l15, f32x4 acc[2][4]) {
  int m0 = rg * 32 + l15;
  int m1 = m0 + 16;
#pragma unroll
  for (int kc = 0; kc < 8; kc++) {
    int sq = kc * 4 + quad;
    short8 a0 = *(const short8*)(act + m0 * 256 + ((sq ^ (m0 & 31)) << 3));
    short8 a1 = *(const short8*)(act + m1 * 256 + ((sq ^ (m1 & 31)) << 3));
#pragma unroll
    for (int i = 0; i < 4; i++) {
      int n = cg * 64 + i * 16 + l15;
      short8 b = *(const short8*)(wbuf + n * 256 + ((sq ^ (n & 31)) << 3));
      acc[0][i] = __builtin_amdgcn_mfma_f32_16x16x32_bf16(a0, b, acc[0][i], 0, 0, 0);
      acc[1][i] = __builtin_amdgcn_mfma_f32_16x16x32_bf16(a1, b, acc[1][i], 0, 0, 0);
    }
  }
}

__global__ void __launch_bounds__(512, 2) nerf_fused(
    const float* __restrict__ rays_o, const float* __restrict__ rays_d,
    const float* __restrict__ t_rand,
    const float* __restrict__ W1, const float* __restrict__ b1,
    const float* __restrict__ b2, const float* __restrict__ b3,
    const float* __restrict__ Wd, const float* __restrict__ bd,
    const float* __restrict__ W4, const float* __restrict__ b4,
    const float* __restrict__ W5, const float* __restrict__ b5,
    const u16* __restrict__ wpack, float* __restrict__ out) {
  extern __shared__ char lds[];
  u16*   act   = (u16*)(lds + OFF_ACT);
  u16*   wbuf  = (u16*)(lds + OFF_WBUF);
  float* zv    = (float*)(lds + OFF_ZV);
  float* dist  = (float*)(lds + OFF_DIST);
  float* dens  = (float*)(lds + OFF_DENS);
  float* rgbL  = (float*)(lds + OFF_RGB);
  float* vdirL = (float*)(lds + OFF_VDIR);
  float* w5L   = (float*)(lds + OFF_W5);
  float* b5L   = (float*)(lds + OFF_B5);

  const int t = threadIdx.x;
  const int lane = t & 63;
  const int wv = t >> 6;        // 0..7
  const int quad = lane >> 4;
  const int l15 = lane & 15;
  const int rg = wv >> 1;       // 0..3 : rows rg*32..+31
  const int cg = wv & 1;        // 0..1 : cols cg*64..+63 within chunk
  const int ray0 = blockIdx.x * 2;

  // ---- setup: z_vals, view dirs, W5/b5 preload ----
  if (t < 128) {
    int m = t, r = m >> 6, j = m & 63;
    float fj = (float)j;
    float zj = 0.5f + 2.0f * (fj / 63.0f);
    float lower = (j == 0)  ? zj : 0.5f * (zj + (0.5f + 2.0f * ((fj - 1.0f) / 63.0f)));
    float upper = (j == 63) ? zj : 0.5f * (zj + (0.5f + 2.0f * ((fj + 1.0f) / 63.0f)));
    float tr = t_rand[(ray0 + r) * 64 + j];
    zv[m] = lower + (upper - lower) * tr;
  } else {
    w5L[t - 128] = W5[t - 128];   // 384 elems, threads 128..511
  }
  if (t < 4) b5L[t] = (t < 3) ? b5[t] : 0.f;
  if (t < 2) {
    float dx = rays_d[(ray0 + t) * 3 + 0];
    float dy = rays_d[(ray0 + t) * 3 + 1];
    float dz = rays_d[(ray0 + t) * 3 + 2];
    float nrm = sqrtf(dx * dx + dy * dy + dz * dz) + 1e-8f;
    vdirL[t * 4 + 0] = dx / nrm; vdirL[t * 4 + 1] = dy / nrm; vdirL[t * 4 + 2] = dz / nrm;
  }
  __syncthreads();

  if (t < 128) {
    int j = t & 63;
    dist[t] = (j < 63) ? (zv[t + 1] - zv[t]) : 1e10f;
  }

  // ---- layer 1: h1 = relu(pts@W1 + b1) -> act (bf16, swizzled) ----
  {
    int m = t >> 2, p = t & 3, r = m >> 6;
    float zm = zv[m];
    float ox = rays_o[(ray0 + r) * 3 + 0];
    float oy = rays_o[(ray0 + r) * 3 + 1];
    float oz = rays_o[(ray0 + r) * 3 + 2];
    float dx = rays_d[(ray0 + r) * 3 + 0];
    float dy = rays_d[(ray0 + r) * 3 + 1];
    float dz = rays_d[(ray0 + r) * 3 + 2];
    float px = ox + dx * zm, py = oy + dy * zm, pz = oz + dz * zm;
#pragma unroll
    for (int kk = 0; kk < 64; kk += 8) {
      int k0 = p * 64 + kk;
      float4 bva = *(const float4*)(b1 + k0);
      float4 bvb = *(const float4*)(b1 + k0 + 4);
      float4 w0a = *(const float4*)(W1 + k0);
      float4 w0b = *(const float4*)(W1 + k0 + 4);
      float4 w1a = *(const float4*)(W1 + 256 + k0);
      float4 w1b = *(const float4*)(W1 + 256 + k0 + 4);
      float4 w2a = *(const float4*)(W1 + 512 + k0);
      float4 w2b = *(const float4*)(W1 + 512 + k0 + 4);
      float bb[8] = {bva.x, bva.y, bva.z, bva.w, bvb.x, bvb.y, bvb.z, bvb.w};
      float w0[8] = {w0a.x, w0a.y, w0a.z, w0a.w, w0b.x, w0b.y, w0b.z, w0b.w};
      float w1[8] = {w1a.x, w1a.y, w1a.z, w1a.w, w1b.x, w1b.y, w1b.z, w1b.w};
      float w2[8] = {w2a.x, w2a.y, w2a.z, w2a.w, w2b.x, w2b.y, w2b.z, w2b.w};
      union { u16 a[8]; short8 v; } res;
#pragma unroll
      for (int j = 0; j < 8; j++) {
        float s = bb[j] + px * w0[j] + py * w1[j] + pz * w2[j];
        res.a[j] = f2bf(fmaxf(s, 0.f));
      }
      int u = (k0 >> 3) ^ (m & 31);
      *(short8*)(act + m * 256 + u * 8) = res.v;
    }
  }
  __syncthreads();

  // ---- layers 2 & 3: h = relu(h@W + b), K=256, N=256 (2 chunks of 128 cols) ----
  const u16* wsrc0 = wpack;
  const u16* wsrc1 = wpack + 65536;
#pragma unroll 1
  for (int L = 0; L < 2; L++) {
    const u16* wsrc = (L == 0) ? wsrc0 : wsrc1;
    const float* bb = (L == 0) ? b2 : b3;
    f32x4 acc[2][2][4];
#pragma unroll
    for (int c = 0; c < 2; c++)
#pragma unroll
      for (int a = 0; a < 2; a++)
#pragma unroll
        for (int i = 0; i < 4; i++) acc[c][a][i] = (f32x4){0.f, 0.f, 0.f, 0.f};
#pragma unroll 1
    for (int c = 0; c < 2; c++) {
      stage64k(wsrc + c * 32768, wbuf, t);
      __syncthreads();                 // wbuf ready
      kloop(act, wbuf, rg, cg, quad, l15, acc[c]);
      __syncthreads();                 // all reads of wbuf/act for this chunk done
    }
    // epilogue: relu(acc+bias) -> act in place
#pragma unroll
    for (int c = 0; c < 2; c++)
#pragma unroll
      for (int a = 0; a < 2; a++) {
        int mbase = rg * 32 + a * 16 + quad * 4;
#pragma unroll
        for (int i = 0; i < 4; i++) {
          int ng = c * 128 + cg * 64 + i * 16 + l15;
          float bias = bb[ng];
#pragma unroll
          for (int r = 0; r < 4; r++) {
            int mm = mbase + r;
            float v = fmaxf(acc[c][a][i][r] + bias, 0.f);
            act[mm * 256 + (((ng >> 3) ^ (mm & 31)) << 3) + (ng & 7)] = f2bf(v);
          }
        }
      }
    __syncthreads();
  }

  // ---- density (fp32 dot over h3), then W4t staging ----
  {
    int m = t >> 2, p = t & 3;
    float s = 0.f;
#pragma unroll
    for (int kk = 0; kk < 64; kk += 8) {
      int k0 = p * 64 + kk;
      short8 h = *(const short8*)(act + m * 256 + (((k0 >> 3) ^ (m & 31)) << 3));
      float4 wa = *(const float4*)(Wd + k0);
      float4 wb = *(const float4*)(Wd + k0 + 4);
      float w[8] = {wa.x, wa.y, wa.z, wa.w, wb.x, wb.y, wb.z, wb.w};
#pragma unroll
      for (int j = 0; j < 8; j++) s += bf2f((u16)h[j]) * w[j];
    }
    s += __shfl_xor(s, 1);
    s += __shfl_xor(s, 2);
    if (p == 0) dens[m] = s + bd[0];
  }
  stage64k(wpack + 131072, wbuf, t);
  __syncthreads();

  // ---- layer 4: h4 = relu(h3@W4[:256] + vdir@W4[256:259] + b4), N=128 ----
  {
    f32x4 acc[2][4];
#pragma unroll
    for (int a = 0; a < 2; a++)
#pragma unroll
      for (int i = 0; i < 4; i++) acc[a][i] = (f32x4){0.f, 0.f, 0.f, 0.f};
    kloop(act, wbuf, rg, cg, quad, l15, acc);
    __syncthreads();                   // done reading h3 from act
    int rw = rg >> 1;                  // ray within block (wave-uniform)
    float v0 = vdirL[rw * 4 + 0], v1 = vdirL[rw * 4 + 1], v2 = vdirL[rw * 4 + 2];
#pragma unroll
    for (int a = 0; a < 2; a++) {
      int mbase = rg * 32 + a * 16 + quad * 4;
#pragma unroll
      for (int i = 0; i < 4; i++) {
        int n = cg * 64 + i * 16 + l15;
        float add = b4[n] + v0 * W4[32768 + n] + v1 * W4[32896 + n] + v2 * W4[33024 + n];
#pragma unroll
        for (int r = 0; r < 4; r++) {
          int mm = mbase + r;
          float v = fmaxf(acc[a][i][r] + add, 0.f);
          act[mm * 256 + (((n >> 3) ^ (mm & 31)) << 3) + (n & 7)] = f2bf(v);
        }
      }
    }
  }
  __syncthreads();

  // ---- rgb = sigmoid(h4@W5 + b5) (fp32 VALU) ----
  {
    int m = t >> 2, p = t & 3;
    float s0 = 0.f, s1 = 0.f, s2 = 0.f;
#pragma unroll
    for (int kk = 0; kk < 32; kk += 8) {
      int k0 = p * 32 + kk;
      short8 h = *(const short8*)(act + m * 256 + (((k0 >> 3) ^ (m & 31)) << 3));
#pragma unroll
      for (int j = 0; j < 8; j++) {
        float hv = bf2f((u16)h[j]);
        int k = k0 + j;
        s0 += hv * w5L[k * 3 + 0];
        s1 += hv * w5L[k * 3 + 1];
        s2 += hv * w5L[k * 3 + 2];
      }
    }
    s0 += __shfl_xor(s0, 1); s0 += __shfl_xor(s0, 2);
    s1 += __shfl_xor(s1, 1); s1 += __shfl_xor(s1, 2);
    s2 += __shfl_xor(s2, 1); s2 += __shfl_xor(s2, 2);
    if (p == 0) {
      rgbL[m * 4 + 0] = 1.f / (1.f + __expf(-(s0 + b5L[0])));
      rgbL[m * 4 + 1] = 1.f / (1.f + __expf(-(s1 + b5L[1])));
      rgbL[m * 4 + 2] = 1.f / (1.f + __expf(-(s2 + b5L[2])));
    }
  }
  __syncthreads();

  // ---- alpha compositing: one wave per ray ----
  if (t < 128) {
    int r = t >> 6, j = t & 63, m = t;
    float alpha = 1.f - __expf(-fmaxf(dens[m], 0.f) * dist[m]);
    float v = 1.f - alpha + 1e-10f;
    float pscan = v;
#pragma unroll
    for (int d = 1; d < 64; d <<= 1) {
      float o = __shfl_up(pscan, d);
      if (j >= d) pscan *= o;
    }
    float T = __shfl_up(pscan, 1);
    if (j == 0) T = 1.f;
    float w = alpha * T;
    float r0 = w * rgbL[m * 4 + 0];
    float r1 = w * rgbL[m * 4 + 1];
    float r2 = w * rgbL[m * 4 + 2];
    float dp = w * zv[m];
    float ac = w;
#pragma unroll
    for (int d = 32; d; d >>= 1) {
      r0 += __shfl_down(r0, d);
      r1 += __shfl_down(r1, d);
      r2 += __shfl_down(r2, d);
      dp += __shfl_down(dp, d);
      ac += __shfl_down(ac, d);
    }
    if (j == 0) {
      int ray = ray0 + r;
      float bg = 1.f - ac;
      out[ray * 3 + 0] = r0 + bg;
      out[ray * 3 + 1] = r1 + bg;
      out[ray * 3 + 2] = r2 + bg;
      out[NRAYS * 3 + ray] = dp;
      out[NRAYS * 4 + ray] = ac;
    }
  }
}

extern "C" void kernel_launch(void* const* d_in, const int* in_sizes, int n_in,
                              void* d_out, int out_size, void* d_ws, size_t ws_size,
                              hipStream_t stream) {
  const float* rays_o = (const float*)d_in[0];
  const float* rays_d = (const float*)d_in[1];
  const float* t_rand = (const float*)d_in[2];
  const float* W1 = (const float*)d_in[3];
  const float* b1 = (const float*)d_in[4];
  const float* W2 = (const float*)d_in[5];
  const float* b2 = (const float*)d_in[6];
  const float* W3 = (const float*)d_in[7];
  const float* b3 = (const float*)d_in[8];
  const float* Wd = (const float*)d_in[9];
  const float* bd = (const float*)d_in[10];
  const float* W4 = (const float*)d_in[11];
  const float* b4 = (const float*)d_in[12];
  const float* W5 = (const float*)d_in[13];
  const float* b5 = (const float*)d_in[14];
  u16* wpack = (u16*)d_ws;
  float* out = (float*)d_out;

  (void)hipFuncSetAttribute((const void*)nerf_fused,
                            hipFuncAttributeMaxDynamicSharedMemorySize, LDS_TOTAL);
  pack_weights<<<640, 256, 0, stream>>>(W2, W3, W4, wpack);
  nerf_fused<<<2048, 512, LDS_TOTAL, stream>>>(rays_o, rays_d, t_rand, W1, b1, b2, b3,
                                               Wd, bd, W4, b4, W5, b5, wpack, out);
}

// Round 4
// 557.736 us; speedup vs baseline: 1.0300x; 1.0300x over previous
//
#include <hip/hip_runtime.h>
#include <stdint.h>

// R4: (1) kill scratch arrays (R3's 1.04 GB WRITE_SIZE = demoted float[8] arrays);
//     (2) restructure: 1 ray/block (M=64, 256thr/4waves), act 32KB LDS (static),
//         B streamed global->regs from packed [n][k] weights (L2-resident),
//         NO staging barriers in K-loop. 4 blocks/CU.

#define NRAYS 4096

typedef unsigned short u16;
typedef __attribute__((ext_vector_type(8))) short short8;
typedef __attribute__((ext_vector_type(4))) float f32x4;

__device__ __forceinline__ u16 f2bf(float f) {
  union { float f; uint32_t i; } v; v.f = f;
  return (u16)((v.i + 0x7FFFu + ((v.i >> 16) & 1u)) >> 16);
}
__device__ __forceinline__ float bf2f(u16 u) {
  union { uint32_t i; float f; } v; v.i = ((uint32_t)u) << 16; return v.f;
}

// ---------------- weight transpose + fp32->bf16 convert into workspace ----------------
// ws (bf16 elems): W2t [256n][256k] @0, W3t [256n][256k] @65536, W4t [128n][256k] @131072
__global__ void pack_weights(const float* __restrict__ W2, const float* __restrict__ W3,
                             const float* __restrict__ W4, u16* __restrict__ ws) {
  int idx = blockIdx.x * 256 + threadIdx.x;   // grid covers exactly 163840
  float v;
  if (idx < 65536) {
    int n = idx >> 8, k = idx & 255;
    v = W2[k * 256 + n];
  } else if (idx < 131072) {
    int o = idx - 65536, n = o >> 8, k = o & 255;
    v = W3[k * 256 + n];
  } else {
    int o = idx - 131072, n = o >> 8, k = o & 255;
    v = W4[k * 128 + n];
  }
  ws[idx] = f2bf(v);
}

#define MFMA __builtin_amdgcn_mfma_f32_16x16x32_bf16

// K=256 pass, 64 rows (all in LDS act), 64 cols per wave streamed from global wB.
__device__ __forceinline__ void kloop256(const u16* __restrict__ act, const u16* __restrict__ wB,
                                         int colbase, int quad, int l15, f32x4 acc[4][4]) {
  const int m0 = l15, m1 = l15 + 16, m2 = l15 + 32, m3 = l15 + 48;
  const u16* bp0 = wB + (colbase +  0 + l15) * 256;
  const u16* bp1 = wB + (colbase + 16 + l15) * 256;
  const u16* bp2 = wB + (colbase + 32 + l15) * 256;
  const u16* bp3 = wB + (colbase + 48 + l15) * 256;
#pragma unroll
  for (int kc = 0; kc < 8; kc++) {
    int sq = kc * 4 + quad;
    short8 b0 = *(const short8*)(bp0 + sq * 8);
    short8 b1 = *(const short8*)(bp1 + sq * 8);
    short8 b2 = *(const short8*)(bp2 + sq * 8);
    short8 b3 = *(const short8*)(bp3 + sq * 8);
    short8 a0 = *(const short8*)(act + m0 * 256 + ((sq ^ (m0 & 31)) << 3));
    short8 a1 = *(const short8*)(act + m1 * 256 + ((sq ^ (m1 & 31)) << 3));
    short8 a2 = *(const short8*)(act + m2 * 256 + ((sq ^ (m2 & 31)) << 3));
    short8 a3 = *(const short8*)(act + m3 * 256 + ((sq ^ (m3 & 31)) << 3));
    acc[0][0] = MFMA(a0, b0, acc[0][0], 0, 0, 0);
    acc[1][0] = MFMA(a1, b0, acc[1][0], 0, 0, 0);
    acc[2][0] = MFMA(a2, b0, acc[2][0], 0, 0, 0);
    acc[3][0] = MFMA(a3, b0, acc[3][0], 0, 0, 0);
    acc[0][1] = MFMA(a0, b1, acc[0][1], 0, 0, 0);
    acc[1][1] = MFMA(a1, b1, acc[1][1], 0, 0, 0);
    acc[2][1] = MFMA(a2, b1, acc[2][1], 0, 0, 0);
    acc[3][1] = MFMA(a3, b1, acc[3][1], 0, 0, 0);
    acc[0][2] = MFMA(a0, b2, acc[0][2], 0, 0, 0);
    acc[1][2] = MFMA(a1, b2, acc[1][2], 0, 0, 0);
    acc[2][2] = MFMA(a2, b2, acc[2][2], 0, 0, 0);
    acc[3][2] = MFMA(a3, b2, acc[3][2], 0, 0, 0);
    acc[0][3] = MFMA(a0, b3, acc[0][3], 0, 0, 0);
    acc[1][3] = MFMA(a1, b3, acc[1][3], 0, 0, 0);
    acc[2][3] = MFMA(a2, b3, acc[2][3], 0, 0, 0);
    acc[3][3] = MFMA(a3, b3, acc[3][3], 0, 0, 0);
  }
}

// K=256 pass, 64 rows, 32 cols per wave (layer 4, N=128).
__device__ __forceinline__ void kloop128(const u16* __restrict__ act, const u16* __restrict__ wB,
                                         int colbase, int quad, int l15, f32x4 acc[4][2]) {
  const int m0 = l15, m1 = l15 + 16, m2 = l15 + 32, m3 = l15 + 48;
  const u16* bp0 = wB + (colbase +  0 + l15) * 256;
  const u16* bp1 = wB + (colbase + 16 + l15) * 256;
#pragma unroll
  for (int kc = 0; kc < 8; kc++) {
    int sq = kc * 4 + quad;
    short8 b0 = *(const short8*)(bp0 + sq * 8);
    short8 b1 = *(const short8*)(bp1 + sq * 8);
    short8 a0 = *(const short8*)(act + m0 * 256 + ((sq ^ (m0 & 31)) << 3));
    short8 a1 = *(const short8*)(act + m1 * 256 + ((sq ^ (m1 & 31)) << 3));
    short8 a2 = *(const short8*)(act + m2 * 256 + ((sq ^ (m2 & 31)) << 3));
    short8 a3 = *(const short8*)(act + m3 * 256 + ((sq ^ (m3 & 31)) << 3));
    acc[0][0] = MFMA(a0, b0, acc[0][0], 0, 0, 0);
    acc[1][0] = MFMA(a1, b0, acc[1][0], 0, 0, 0);
    acc[2][0] = MFMA(a2, b0, acc[2][0], 0, 0, 0);
    acc[3][0] = MFMA(a3, b0, acc[3][0], 0, 0, 0);
    acc[0][1] = MFMA(a0, b1, acc[0][1], 0, 0, 0);
    acc[1][1] = MFMA(a1, b1, acc[1][1], 0, 0, 0);
    acc[2][1] = MFMA(a2, b1, acc[2][1], 0, 0, 0);
    acc[3][1] = MFMA(a3, b1, acc[3][1], 0, 0, 0);
  }
}

__global__ void __launch_bounds__(256, 4) nerf_fused(
    const float* __restrict__ rays_o, const float* __restrict__ rays_d,
    const float* __restrict__ t_rand,
    const float* __restrict__ W1, const float* __restrict__ b1,
    const float* __restrict__ b2, const float* __restrict__ b3,
    const float* __restrict__ Wd, const float* __restrict__ bd,
    const float* __restrict__ W4, const float* __restrict__ b4,
    const float* __restrict__ W5, const float* __restrict__ b5,
    const u16* __restrict__ wpack, float* __restrict__ out) {
  __shared__ u16   act[64 * 256];    // 32 KB, XOR-swizzled slots
  __shared__ float zv[64];
  __shared__ float dist[64];
  __shared__ float dens[64];
  __shared__ float rgbL[64 * 4];
  __shared__ float vdirL[4];
  __shared__ float w5L[384];
  __shared__ float b5L[4];

  const int t = threadIdx.x;
  const int lane = t & 63;
  const int wv = t >> 6;        // 0..3
  const int quad = lane >> 4;
  const int l15 = lane & 15;
  const int ray = blockIdx.x;

  // ---- setup ----
  if (t < 64) {
    int j = t;
    float fj = (float)j;
    float zj = 0.5f + 2.0f * (fj / 63.0f);
    float lower = (j == 0)  ? zj : 0.5f * (zj + (0.5f + 2.0f * ((fj - 1.0f) / 63.0f)));
    float upper = (j == 63) ? zj : 0.5f * (zj + (0.5f + 2.0f * ((fj + 1.0f) / 63.0f)));
    float tr = t_rand[ray * 64 + j];
    zv[j] = lower + (upper - lower) * tr;
  } else {
    int idx = t - 64;                 // 0..191
    w5L[idx] = W5[idx];
    w5L[idx + 192] = W5[idx + 192];
  }
  if (t < 3) b5L[t] = b5[t];
  if (t == 0) {
    float dx = rays_d[ray * 3 + 0];
    float dy = rays_d[ray * 3 + 1];
    float dz = rays_d[ray * 3 + 2];
    float nrm = sqrtf(dx * dx + dy * dy + dz * dz) + 1e-8f;
    vdirL[0] = dx / nrm; vdirL[1] = dy / nrm; vdirL[2] = dz / nrm;
  }
  __syncthreads();

  if (t < 64) dist[t] = (t < 63) ? (zv[t + 1] - zv[t]) : 1e10f;

  // ---- layer 1: h1 = relu(pts@W1 + b1) -> act (pure vector ops, no C arrays) ----
  {
    int m = t >> 2, p = t & 3;
    float zm = zv[m];
    float px = rays_o[ray * 3 + 0] + rays_d[ray * 3 + 0] * zm;
    float py = rays_o[ray * 3 + 1] + rays_d[ray * 3 + 1] * zm;
    float pz = rays_o[ray * 3 + 2] + rays_d[ray * 3 + 2] * zm;
#pragma unroll
    for (int kk = 0; kk < 64; kk += 8) {
      int k0 = p * 64 + kk;
      f32x4 bva = *(const f32x4*)(b1 + k0);
      f32x4 bvb = *(const f32x4*)(b1 + k0 + 4);
      f32x4 w0a = *(const f32x4*)(W1 + k0);
      f32x4 w0b = *(const f32x4*)(W1 + k0 + 4);
      f32x4 w1a = *(const f32x4*)(W1 + 256 + k0);
      f32x4 w1b = *(const f32x4*)(W1 + 256 + k0 + 4);
      f32x4 w2a = *(const f32x4*)(W1 + 512 + k0);
      f32x4 w2b = *(const f32x4*)(W1 + 512 + k0 + 4);
      f32x4 sa = bva + px * w0a + py * w1a + pz * w2a;
      f32x4 sb = bvb + px * w0b + py * w1b + pz * w2b;
      short8 res;
      res[0] = (short)f2bf(fmaxf(sa[0], 0.f));
      res[1] = (short)f2bf(fmaxf(sa[1], 0.f));
      res[2] = (short)f2bf(fmaxf(sa[2], 0.f));
      res[3] = (short)f2bf(fmaxf(sa[3], 0.f));
      res[4] = (short)f2bf(fmaxf(sb[0], 0.f));
      res[5] = (short)f2bf(fmaxf(sb[1], 0.f));
      res[6] = (short)f2bf(fmaxf(sb[2], 0.f));
      res[7] = (short)f2bf(fmaxf(sb[3], 0.f));
      int u = (k0 >> 3) ^ (m & 31);
      *(short8*)(act + m * 256 + u * 8) = res;
    }
  }
  __syncthreads();

  // ---- layers 2 & 3: h = relu(h@W + b), K=256, N=256, B streamed from L2 ----
#pragma unroll 1
  for (int L = 0; L < 2; L++) {
    const u16* wB = wpack + L * 65536;
    const float* bb = (L == 0) ? b2 : b3;
    f32x4 acc[4][4];
#pragma unroll
    for (int a = 0; a < 4; a++)
#pragma unroll
      for (int i = 0; i < 4; i++) acc[a][i] = (f32x4){0.f, 0.f, 0.f, 0.f};
    kloop256(act, wB, wv * 64, quad, l15, acc);
    __syncthreads();               // all act reads done before in-place rewrite
#pragma unroll
    for (int i = 0; i < 4; i++) {
      int ng = wv * 64 + i * 16 + l15;
      float bias = bb[ng];
      int su = (ng >> 3), so = (ng & 7);
#pragma unroll
      for (int mt = 0; mt < 4; mt++) {
        int mb = mt * 16 + quad * 4;
#pragma unroll
        for (int r = 0; r < 4; r++) {
          int mm = mb + r;
          act[mm * 256 + ((su ^ (mm & 31)) << 3) + so] = f2bf(fmaxf(acc[mt][i][r] + bias, 0.f));
        }
      }
    }
    __syncthreads();
  }

  // ---- density: fp32 dot(h3, Wd) ----
  {
    int m = t >> 2, p = t & 3;
    float s = 0.f;
#pragma unroll
    for (int kk = 0; kk < 64; kk += 8) {
      int k0 = p * 64 + kk;
      short8 h = *(const short8*)(act + m * 256 + (((k0 >> 3) ^ (m & 31)) << 3));
      f32x4 wa = *(const f32x4*)(Wd + k0);
      f32x4 wb = *(const f32x4*)(Wd + k0 + 4);
      s += bf2f((u16)h[0]) * wa[0] + bf2f((u16)h[1]) * wa[1]
         + bf2f((u16)h[2]) * wa[2] + bf2f((u16)h[3]) * wa[3]
         + bf2f((u16)h[4]) * wb[0] + bf2f((u16)h[5]) * wb[1]
         + bf2f((u16)h[6]) * wb[2] + bf2f((u16)h[7]) * wb[3];
    }
    s += __shfl_xor(s, 1);
    s += __shfl_xor(s, 2);
    if (p == 0) dens[m] = s + bd[0];
  }

  // ---- layer 4: h4 = relu(h3@W4[:256] + vdir@W4[256:259] + b4), N=128 ----
  {
    f32x4 acc[4][2];
#pragma unroll
    for (int a = 0; a < 4; a++)
#pragma unroll
      for (int i = 0; i < 2; i++) acc[a][i] = (f32x4){0.f, 0.f, 0.f, 0.f};
    kloop128(act, wpack + 131072, wv * 32, quad, l15, acc);
    __syncthreads();               // all h3 reads done (incl. density) before rewrite
    float v0 = vdirL[0], v1 = vdirL[1], v2 = vdirL[2];
#pragma unroll
    for (int i = 0; i < 2; i++) {
      int ng = wv * 32 + i * 16 + l15;
      float add = b4[ng] + v0 * W4[32768 + ng] + v1 * W4[32896 + ng] + v2 * W4[33024 + ng];
      int su = (ng >> 3), so = (ng & 7);
#pragma unroll
      for (int mt = 0; mt < 4; mt++) {
        int mb = mt * 16 + quad * 4;
#pragma unroll
        for (int r = 0; r < 4; r++) {
          int mm = mb + r;
          act[mm * 256 + ((su ^ (mm & 31)) << 3) + so] = f2bf(fmaxf(acc[mt][i][r] + add, 0.f));
        }
      }
    }
  }
  __syncthreads();

  // ---- rgb = sigmoid(h4@W5 + b5) ----
  {
    int m = t >> 2, p = t & 3;
    float s0 = 0.f, s1 = 0.f, s2 = 0.f;
#pragma unroll
    for (int kk = 0; kk < 32; kk += 8) {
      int k0 = p * 32 + kk;
      short8 h = *(const short8*)(act + m * 256 + (((k0 >> 3) ^ (m & 31)) << 3));
#pragma unroll
      for (int j = 0; j < 8; j++) {
        float hv = bf2f((u16)h[j]);
        int k = k0 + j;
        s0 += hv * w5L[k * 3 + 0];
        s1 += hv * w5L[k * 3 + 1];
        s2 += hv * w5L[k * 3 + 2];
      }
    }
    s0 += __shfl_xor(s0, 1); s0 += __shfl_xor(s0, 2);
    s1 += __shfl_xor(s1, 1); s1 += __shfl_xor(s1, 2);
    s2 += __shfl_xor(s2, 1); s2 += __shfl_xor(s2, 2);
    if (p == 0) {
      rgbL[m * 4 + 0] = 1.f / (1.f + __expf(-(s0 + b5L[0])));
      rgbL[m * 4 + 1] = 1.f / (1.f + __expf(-(s1 + b5L[1])));
      rgbL[m * 4 + 2] = 1.f / (1.f + __expf(-(s2 + b5L[2])));
    }
  }
  __syncthreads();

  // ---- alpha compositing: wave 0 handles the block's single ray ----
  if (t < 64) {
    int j = t;
    float alpha = 1.f - __expf(-fmaxf(dens[j], 0.f) * dist[j]);
    float v = 1.f - alpha + 1e-10f;
    float pscan = v;
#pragma unroll
    for (int d = 1; d < 64; d <<= 1) {
      float o = __shfl_up(pscan, d);
      if (j >= d) pscan *= o;
    }
    float T = __shfl_up(pscan, 1);
    if (j == 0) T = 1.f;
    float w = alpha * T;
    float r0 = w * rgbL[j * 4 + 0];
    float r1 = w * rgbL[j * 4 + 1];
    float r2 = w * rgbL[j * 4 + 2];
    float dp = w * zv[j];
    float ac = w;
#pragma unroll
    for (int d = 32; d; d >>= 1) {
      r0 += __shfl_down(r0, d);
      r1 += __shfl_down(r1, d);
      r2 += __shfl_down(r2, d);
      dp += __shfl_down(dp, d);
      ac += __shfl_down(ac, d);
    }
    if (j == 0) {
      float bg = 1.f - ac;
      out[ray * 3 + 0] = r0 + bg;
      out[ray * 3 + 1] = r1 + bg;
      out[ray * 3 + 2] = r2 + bg;
      out[NRAYS * 3 + ray] = dp;
      out[NRAYS * 4 + ray] = ac;
    }
  }
}

extern "C" void kernel_launch(void* const* d_in, const int* in_sizes, int n_in,
                              void* d_out, int out_size, void* d_ws, size_t ws_size,
                              hipStream_t stream) {
  const float* rays_o = (const float*)d_in[0];
  const float* rays_d = (const float*)d_in[1];
  const float* t_rand = (const float*)d_in[2];
  const float* W1 = (const float*)d_in[3];
  const float* b1 = (const float*)d_in[4];
  const float* W2 = (const float*)d_in[5];
  const float* b2 = (const float*)d_in[6];
  const float* W3 = (const float*)d_in[7];
  const float* b3 = (const float*)d_in[8];
  const float* Wd = (const float*)d_in[9];
  const float* bd = (const float*)d_in[10];
  const float* W4 = (const float*)d_in[11];
  const float* b4 = (const float*)d_in[12];
  const float* W5 = (const float*)d_in[13];
  const float* b5 = (const float*)d_in[14];
  u16* wpack = (u16*)d_ws;
  float* out = (float*)d_out;

  pack_weights<<<640, 256, 0, stream>>>(W2, W3, W4, wpack);
  nerf_fused<<<NRAYS, 256, 0, stream>>>(rays_o, rays_d, t_rand, W1, b1, b2, b3,
                                        Wd, bd, W4, b4, W5, b5, wpack, out);
}

// Round 5
// 528.384 us; speedup vs baseline: 1.0872x; 1.0556x over previous
//
#include <hip/hip_runtime.h>
#include <stdint.h>

// R5: de-scratch the MFMA path. R3/R4 both showed ~0.7-1.0 GB of phantom HBM
// writes == accumulator arrays passed by pointer into kloop* (array decay ->
// alloca -> scratch spill around barriers). K-loops are now macros inlined in
// the kernel body; accumulators are 16 individually-named f32x4 registers.
// Structure otherwise identical to R4 (1 ray/block, M=64, 256 thr, B streamed
// from packed [n][k] weights in L2).

#define NRAYS 4096

typedef unsigned short u16;
typedef __attribute__((ext_vector_type(8))) short short8;
typedef __attribute__((ext_vector_type(4))) float f32x4;

__device__ __forceinline__ u16 f2bf(float f) {
  union { float f; uint32_t i; } v; v.f = f;
  return (u16)((v.i + 0x7FFFu + ((v.i >> 16) & 1u)) >> 16);
}
__device__ __forceinline__ float bf2f(u16 u) {
  union { uint32_t i; float f; } v; v.i = ((uint32_t)u) << 16; return v.f;
}

// ---------------- weight transpose + fp32->bf16 convert into workspace ----------------
// ws (bf16 elems): W2t [256n][256k] @0, W3t [256n][256k] @65536, W4t [128n][256k] @131072
__global__ void pack_weights(const float* __restrict__ W2, const float* __restrict__ W3,
                             const float* __restrict__ W4, u16* __restrict__ ws) {
  int idx = blockIdx.x * 256 + threadIdx.x;   // grid covers exactly 163840
  float v;
  if (idx < 65536) {
    int n = idx >> 8, k = idx & 255;
    v = W2[k * 256 + n];
  } else if (idx < 131072) {
    int o = idx - 65536, n = o >> 8, k = o & 255;
    v = W3[k * 256 + n];
  } else {
    int o = idx - 131072, n = o >> 8, k = o & 255;
    v = W4[k * 128 + n];
  }
  ws[idx] = f2bf(v);
}

#define MFMA __builtin_amdgcn_mfma_f32_16x16x32_bf16

#define ZER4 (f32x4){0.f, 0.f, 0.f, 0.f}

// one K-step (K=32) of the 4-col-tile GEMM: 4 B loads (global), 4 A loads (LDS), 16 MFMA
#define KSTEP4(sq_) do {                                                     \
    const int sq = (sq_);                                                    \
    short8 bv0 = *(const short8*)(bp0 + sq * 8);                             \
    short8 bv1 = *(const short8*)(bp1 + sq * 8);                             \
    short8 bv2 = *(const short8*)(bp2 + sq * 8);                             \
    short8 bv3 = *(const short8*)(bp3 + sq * 8);                             \
    short8 av0 = *(const short8*)(act + m0 * 256 + ((sq ^ (m0 & 31)) << 3)); \
    short8 av1 = *(const short8*)(act + m1 * 256 + ((sq ^ (m1 & 31)) << 3)); \
    short8 av2 = *(const short8*)(act + m2 * 256 + ((sq ^ (m2 & 31)) << 3)); \
    short8 av3 = *(const short8*)(act + m3 * 256 + ((sq ^ (m3 & 31)) << 3)); \
    c00 = MFMA(av0, bv0, c00, 0, 0, 0); c10 = MFMA(av1, bv0, c10, 0, 0, 0);  \
    c20 = MFMA(av2, bv0, c20, 0, 0, 0); c30 = MFMA(av3, bv0, c30, 0, 0, 0);  \
    c01 = MFMA(av0, bv1, c01, 0, 0, 0); c11 = MFMA(av1, bv1, c11, 0, 0, 0);  \
    c21 = MFMA(av2, bv1, c21, 0, 0, 0); c31 = MFMA(av3, bv1, c31, 0, 0, 0);  \
    c02 = MFMA(av0, bv2, c02, 0, 0, 0); c12 = MFMA(av1, bv2, c12, 0, 0, 0);  \
    c22 = MFMA(av2, bv2, c22, 0, 0, 0); c32 = MFMA(av3, bv2, c32, 0, 0, 0);  \
    c03 = MFMA(av0, bv3, c03, 0, 0, 0); c13 = MFMA(av1, bv3, c13, 0, 0, 0);  \
    c23 = MFMA(av2, bv3, c23, 0, 0, 0); c33 = MFMA(av3, bv3, c33, 0, 0, 0);  \
  } while (0)

// one K-step of the 2-col-tile GEMM (layer 4)
#define KSTEP2(sq_) do {                                                     \
    const int sq = (sq_);                                                    \
    short8 bv0 = *(const short8*)(bp0 + sq * 8);                             \
    short8 bv1 = *(const short8*)(bp1 + sq * 8);                             \
    short8 av0 = *(const short8*)(act + m0 * 256 + ((sq ^ (m0 & 31)) << 3)); \
    short8 av1 = *(const short8*)(act + m1 * 256 + ((sq ^ (m1 & 31)) << 3)); \
    short8 av2 = *(const short8*)(act + m2 * 256 + ((sq ^ (m2 & 31)) << 3)); \
    short8 av3 = *(const short8*)(act + m3 * 256 + ((sq ^ (m3 & 31)) << 3)); \
    c00 = MFMA(av0, bv0, c00, 0, 0, 0); c10 = MFMA(av1, bv0, c10, 0, 0, 0);  \
    c20 = MFMA(av2, bv0, c20, 0, 0, 0); c30 = MFMA(av3, bv0, c30, 0, 0, 0);  \
    c01 = MFMA(av0, bv1, c01, 0, 0, 0); c11 = MFMA(av1, bv1, c11, 0, 0, 0);  \
    c21 = MFMA(av2, bv1, c21, 0, 0, 0); c31 = MFMA(av3, bv1, c31, 0, 0, 0);  \
  } while (0)

// store one 16x16 C-tile (named f32x4 CV), row-tile mt, column ng, into swizzled act
#define EPIC(CV, mt, ng, addv) do {                                          \
    int su_ = ((ng) >> 3), so_ = ((ng) & 7);                                 \
    _Pragma("unroll")                                                        \
    for (int r = 0; r < 4; r++) {                                            \
      int mm = (mt) * 16 + quad * 4 + r;                                     \
      act[mm * 256 + ((su_ ^ (mm & 31)) << 3) + so_] =                       \
          f2bf(fmaxf((CV)[r] + (addv), 0.f));                                \
    }                                                                        \
  } while (0)

__global__ void __launch_bounds__(256, 4) nerf_fused(
    const float* __restrict__ rays_o, const float* __restrict__ rays_d,
    const float* __restrict__ t_rand,
    const float* __restrict__ W1, const float* __restrict__ b1,
    const float* __restrict__ b2, const float* __restrict__ b3,
    const float* __restrict__ Wd, const float* __restrict__ bd,
    const float* __restrict__ W4, const float* __restrict__ b4,
    const float* __restrict__ W5, const float* __restrict__ b5,
    const u16* __restrict__ wpack, float* __restrict__ out) {
  __shared__ u16   act[64 * 256];    // 32 KB, XOR-swizzled slots
  __shared__ float zv[64];
  __shared__ float dist[64];
  __shared__ float dens[64];
  __shared__ float rgbL[64 * 4];
  __shared__ float vdirL[4];
  __shared__ float w5L[384];
  __shared__ float b5L[4];

  const int t = threadIdx.x;
  const int lane = t & 63;
  const int wv = t >> 6;        // 0..3
  const int quad = lane >> 4;
  const int l15 = lane & 15;
  const int ray = blockIdx.x;
  const int m0 = l15, m1 = l15 + 16, m2 = l15 + 32, m3 = l15 + 48;

  // ---- setup ----
  if (t < 64) {
    int j = t;
    float fj = (float)j;
    float zj = 0.5f + 2.0f * (fj / 63.0f);
    float lower = (j == 0)  ? zj : 0.5f * (zj + (0.5f + 2.0f * ((fj - 1.0f) / 63.0f)));
    float upper = (j == 63) ? zj : 0.5f * (zj + (0.5f + 2.0f * ((fj + 1.0f) / 63.0f)));
    float tr = t_rand[ray * 64 + j];
    zv[j] = lower + (upper - lower) * tr;
  } else {
    int idx = t - 64;                 // 0..191
    w5L[idx] = W5[idx];
    w5L[idx + 192] = W5[idx + 192];
  }
  if (t < 3) b5L[t] = b5[t];
  if (t == 0) {
    float dx = rays_d[ray * 3 + 0];
    float dy = rays_d[ray * 3 + 1];
    float dz = rays_d[ray * 3 + 2];
    float nrm = sqrtf(dx * dx + dy * dy + dz * dz) + 1e-8f;
    vdirL[0] = dx / nrm; vdirL[1] = dy / nrm; vdirL[2] = dz / nrm;
  }
  __syncthreads();

  if (t < 64) dist[t] = (t < 63) ? (zv[t + 1] - zv[t]) : 1e10f;

  // ---- layer 1: h1 = relu(pts@W1 + b1) -> act (pure vector ops) ----
  {
    int m = t >> 2, p = t & 3;
    float zm = zv[m];
    float px = rays_o[ray * 3 + 0] + rays_d[ray * 3 + 0] * zm;
    float py = rays_o[ray * 3 + 1] + rays_d[ray * 3 + 1] * zm;
    float pz = rays_o[ray * 3 + 2] + rays_d[ray * 3 + 2] * zm;
#pragma unroll
    for (int kk = 0; kk < 64; kk += 8) {
      int k0 = p * 64 + kk;
      f32x4 bva = *(const f32x4*)(b1 + k0);
      f32x4 bvb = *(const f32x4*)(b1 + k0 + 4);
      f32x4 w0a = *(const f32x4*)(W1 + k0);
      f32x4 w0b = *(const f32x4*)(W1 + k0 + 4);
      f32x4 w1a = *(const f32x4*)(W1 + 256 + k0);
      f32x4 w1b = *(const f32x4*)(W1 + 256 + k0 + 4);
      f32x4 w2a = *(const f32x4*)(W1 + 512 + k0);
      f32x4 w2b = *(const f32x4*)(W1 + 512 + k0 + 4);
      f32x4 sa = bva + px * w0a + py * w1a + pz * w2a;
      f32x4 sb = bvb + px * w0b + py * w1b + pz * w2b;
      short8 res;
      res[0] = (short)f2bf(fmaxf(sa[0], 0.f));
      res[1] = (short)f2bf(fmaxf(sa[1], 0.f));
      res[2] = (short)f2bf(fmaxf(sa[2], 0.f));
      res[3] = (short)f2bf(fmaxf(sa[3], 0.f));
      res[4] = (short)f2bf(fmaxf(sb[0], 0.f));
      res[5] = (short)f2bf(fmaxf(sb[1], 0.f));
      res[6] = (short)f2bf(fmaxf(sb[2], 0.f));
      res[7] = (short)f2bf(fmaxf(sb[3], 0.f));
      int u = (k0 >> 3) ^ (m & 31);
      *(short8*)(act + m * 256 + u * 8) = res;
    }
  }
  __syncthreads();

  // ---- layers 2 & 3: h = relu(h@W + b), K=256, N=256, B streamed from L2 ----
#pragma unroll 1
  for (int L = 0; L < 2; L++) {
    const u16* wB = wpack + L * 65536;
    const float* bb = (L == 0) ? b2 : b3;
    const u16* bp0 = wB + (wv * 64 +  0 + l15) * 256;
    const u16* bp1 = wB + (wv * 64 + 16 + l15) * 256;
    const u16* bp2 = wB + (wv * 64 + 32 + l15) * 256;
    const u16* bp3 = wB + (wv * 64 + 48 + l15) * 256;
    f32x4 c00 = ZER4, c01 = ZER4, c02 = ZER4, c03 = ZER4;
    f32x4 c10 = ZER4, c11 = ZER4, c12 = ZER4, c13 = ZER4;
    f32x4 c20 = ZER4, c21 = ZER4, c22 = ZER4, c23 = ZER4;
    f32x4 c30 = ZER4, c31 = ZER4, c32 = ZER4, c33 = ZER4;
#pragma unroll
    for (int kc = 0; kc < 8; kc++) KSTEP4(kc * 4 + quad);
    __syncthreads();               // all act reads done before in-place rewrite
    {
      int ng0 = wv * 64 + l15;
      float bi0 = bb[ng0], bi1 = bb[ng0 + 16], bi2 = bb[ng0 + 32], bi3 = bb[ng0 + 48];
      EPIC(c00, 0, ng0, bi0); EPIC(c10, 1, ng0, bi0);
      EPIC(c20, 2, ng0, bi0); EPIC(c30, 3, ng0, bi0);
      EPIC(c01, 0, ng0 + 16, bi1); EPIC(c11, 1, ng0 + 16, bi1);
      EPIC(c21, 2, ng0 + 16, bi1); EPIC(c31, 3, ng0 + 16, bi1);
      EPIC(c02, 0, ng0 + 32, bi2); EPIC(c12, 1, ng0 + 32, bi2);
      EPIC(c22, 2, ng0 + 32, bi2); EPIC(c32, 3, ng0 + 32, bi2);
      EPIC(c03, 0, ng0 + 48, bi3); EPIC(c13, 1, ng0 + 48, bi3);
      EPIC(c23, 2, ng0 + 48, bi3); EPIC(c33, 3, ng0 + 48, bi3);
    }
    __syncthreads();
  }

  // ---- density: fp32 dot(h3, Wd) ----
  {
    int m = t >> 2, p = t & 3;
    float s = 0.f;
#pragma unroll
    for (int kk = 0; kk < 64; kk += 8) {
      int k0 = p * 64 + kk;
      short8 h = *(const short8*)(act + m * 256 + (((k0 >> 3) ^ (m & 31)) << 3));
      f32x4 wa = *(const f32x4*)(Wd + k0);
      f32x4 wb = *(const f32x4*)(Wd + k0 + 4);
      s += bf2f((u16)h[0]) * wa[0] + bf2f((u16)h[1]) * wa[1]
         + bf2f((u16)h[2]) * wa[2] + bf2f((u16)h[3]) * wa[3]
         + bf2f((u16)h[4]) * wb[0] + bf2f((u16)h[5]) * wb[1]
         + bf2f((u16)h[6]) * wb[2] + bf2f((u16)h[7]) * wb[3];
    }
    s += __shfl_xor(s, 1);
    s += __shfl_xor(s, 2);
    if (p == 0) dens[m] = s + bd[0];
  }

  // ---- layer 4: h4 = relu(h3@W4[:256] + vdir@W4[256:259] + b4), N=128 ----
  {
    const u16* wB = wpack + 131072;
    const u16* bp0 = wB + (wv * 32 +  0 + l15) * 256;
    const u16* bp1 = wB + (wv * 32 + 16 + l15) * 256;
    f32x4 c00 = ZER4, c01 = ZER4;
    f32x4 c10 = ZER4, c11 = ZER4;
    f32x4 c20 = ZER4, c21 = ZER4;
    f32x4 c30 = ZER4, c31 = ZER4;
#pragma unroll
    for (int kc = 0; kc < 8; kc++) KSTEP2(kc * 4 + quad);
    __syncthreads();               // all h3 reads done (incl. density) before rewrite
    {
      float v0 = vdirL[0], v1 = vdirL[1], v2 = vdirL[2];
      int ng0 = wv * 32 + l15;
      float ad0 = b4[ng0] + v0 * W4[32768 + ng0] + v1 * W4[32896 + ng0] + v2 * W4[33024 + ng0];
      int ng1 = ng0 + 16;
      float ad1 = b4[ng1] + v0 * W4[32768 + ng1] + v1 * W4[32896 + ng1] + v2 * W4[33024 + ng1];
      EPIC(c00, 0, ng0, ad0); EPIC(c10, 1, ng0, ad0);
      EPIC(c20, 2, ng0, ad0); EPIC(c30, 3, ng0, ad0);
      EPIC(c01, 0, ng1, ad1); EPIC(c11, 1, ng1, ad1);
      EPIC(c21, 2, ng1, ad1); EPIC(c31, 3, ng1, ad1);
    }
  }
  __syncthreads();

  // ---- rgb = sigmoid(h4@W5 + b5) ----
  {
    int m = t >> 2, p = t & 3;
    float s0 = 0.f, s1 = 0.f, s2 = 0.f;
#pragma unroll
    for (int kk = 0; kk < 32; kk += 8) {
      int k0 = p * 32 + kk;
      short8 h = *(const short8*)(act + m * 256 + (((k0 >> 3) ^ (m & 31)) << 3));
#pragma unroll
      for (int j = 0; j < 8; j++) {
        float hv = bf2f((u16)h[j]);
        int k = k0 + j;
        s0 += hv * w5L[k * 3 + 0];
        s1 += hv * w5L[k * 3 + 1];
        s2 += hv * w5L[k * 3 + 2];
      }
    }
    s0 += __shfl_xor(s0, 1); s0 += __shfl_xor(s0, 2);
    s1 += __shfl_xor(s1, 1); s1 += __shfl_xor(s1, 2);
    s2 += __shfl_xor(s2, 1); s2 += __shfl_xor(s2, 2);
    if (p == 0) {
      rgbL[m * 4 + 0] = 1.f / (1.f + __expf(-(s0 + b5L[0])));
      rgbL[m * 4 + 1] = 1.f / (1.f + __expf(-(s1 + b5L[1])));
      rgbL[m * 4 + 2] = 1.f / (1.f + __expf(-(s2 + b5L[2])));
    }
  }
  __syncthreads();

  // ---- alpha compositing: wave 0 handles the block's single ray ----
  if (t < 64) {
    int j = t;
    float alpha = 1.f - __expf(-fmaxf(dens[j], 0.f) * dist[j]);
    float v = 1.f - alpha + 1e-10f;
    float pscan = v;
#pragma unroll
    for (int d = 1; d < 64; d <<= 1) {
      float o = __shfl_up(pscan, d);
      if (j >= d) pscan *= o;
    }
    float T = __shfl_up(pscan, 1);
    if (j == 0) T = 1.f;
    float w = alpha * T;
    float r0 = w * rgbL[j * 4 + 0];
    float r1 = w * rgbL[j * 4 + 1];
    float r2 = w * rgbL[j * 4 + 2];
    float dp = w * zv[j];
    float ac = w;
#pragma unroll
    for (int d = 32; d; d >>= 1) {
      r0 += __shfl_down(r0, d);
      r1 += __shfl_down(r1, d);
      r2 += __shfl_down(r2, d);
      dp += __shfl_down(dp, d);
      ac += __shfl_down(ac, d);
    }
    if (j == 0) {
      float bg = 1.f - ac;
      out[ray * 3 + 0] = r0 + bg;
      out[ray * 3 + 1] = r1 + bg;
      out[ray * 3 + 2] = r2 + bg;
      out[NRAYS * 3 + ray] = dp;
      out[NRAYS * 4 + ray] = ac;
    }
  }
}

extern "C" void kernel_launch(void* const* d_in, const int* in_sizes, int n_in,
                              void* d_out, int out_size, void* d_ws, size_t ws_size,
                              hipStream_t stream) {
  const float* rays_o = (const float*)d_in[0];
  const float* rays_d = (const float*)d_in[1];
  const float* t_rand = (const float*)d_in[2];
  const float* W1 = (const float*)d_in[3];
  const float* b1 = (const float*)d_in[4];
  const float* W2 = (const float*)d_in[5];
  const float* b2 = (const float*)d_in[6];
  const float* W3 = (const float*)d_in[7];
  const float* b3 = (const float*)d_in[8];
  const float* Wd = (const float*)d_in[9];
  const float* bd = (const float*)d_in[10];
  const float* W4 = (const float*)d_in[11];
  const float* b4 = (const float*)d_in[12];
  const float* W5 = (const float*)d_in[13];
  const float* b5 = (const float*)d_in[14];
  u16* wpack = (u16*)d_ws;
  float* out = (float*)d_out;

  pack_weights<<<640, 256, 0, stream>>>(W2, W3, W4, wpack);
  nerf_fused<<<NRAYS, 256, 0, stream>>>(rays_o, rays_d, t_rand, W1, b1, b2, b3,
                                        Wd, bd, W4, b4, W5, b5, wpack, out);
}

// Round 6
// 394.559 us; speedup vs baseline: 1.4560x; 1.3392x over previous
//
#include <hip/hip_runtime.h>
#include <stdint.h>

// R6: fix the spill at its root. R3-R5 all ran at 4 waves/EU -> 128-reg budget
// (unified VGPR+AGPR on gfx950); 64 AGPR accs left only 64 arch VGPRs (exactly
// the reported VGPR_Count) -> allocator spilled ~600 B/thread to scratch ->
// 0.6-1.0 GB phantom HBM writes == the entire runtime (dur ~= hbm_bytes/2.35TB/s).
// Change: __launch_bounds__(256, 2) -> 256-reg budget, zero spill, 2 blocks/CU.
// Everything else identical to R5.

#define NRAYS 4096

typedef unsigned short u16;
typedef __attribute__((ext_vector_type(8))) short short8;
typedef __attribute__((ext_vector_type(4))) float f32x4;

__device__ __forceinline__ u16 f2bf(float f) {
  union { float f; uint32_t i; } v; v.f = f;
  return (u16)((v.i + 0x7FFFu + ((v.i >> 16) & 1u)) >> 16);
}
__device__ __forceinline__ float bf2f(u16 u) {
  union { uint32_t i; float f; } v; v.i = ((uint32_t)u) << 16; return v.f;
}

// ---------------- weight transpose + fp32->bf16 convert into workspace ----------------
// ws (bf16 elems): W2t [256n][256k] @0, W3t [256n][256k] @65536, W4t [128n][256k] @131072
__global__ void pack_weights(const float* __restrict__ W2, const float* __restrict__ W3,
                             const float* __restrict__ W4, u16* __restrict__ ws) {
  int idx = blockIdx.x * 256 + threadIdx.x;   // grid covers exactly 163840
  float v;
  if (idx < 65536) {
    int n = idx >> 8, k = idx & 255;
    v = W2[k * 256 + n];
  } else if (idx < 131072) {
    int o = idx - 65536, n = o >> 8, k = o & 255;
    v = W3[k * 256 + n];
  } else {
    int o = idx - 131072, n = o >> 8, k = o & 255;
    v = W4[k * 128 + n];
  }
  ws[idx] = f2bf(v);
}

#define MFMA __builtin_amdgcn_mfma_f32_16x16x32_bf16

#define ZER4 (f32x4){0.f, 0.f, 0.f, 0.f}

// one K-step (K=32) of the 4-col-tile GEMM: 4 B loads (global), 4 A loads (LDS), 16 MFMA
#define KSTEP4(sq_) do {                                                     \
    const int sq = (sq_);                                                    \
    short8 bv0 = *(const short8*)(bp0 + sq * 8);                             \
    short8 bv1 = *(const short8*)(bp1 + sq * 8);                             \
    short8 bv2 = *(const short8*)(bp2 + sq * 8);                             \
    short8 bv3 = *(const short8*)(bp3 + sq * 8);                             \
    short8 av0 = *(const short8*)(act + m0 * 256 + ((sq ^ (m0 & 31)) << 3)); \
    short8 av1 = *(const short8*)(act + m1 * 256 + ((sq ^ (m1 & 31)) << 3)); \
    short8 av2 = *(const short8*)(act + m2 * 256 + ((sq ^ (m2 & 31)) << 3)); \
    short8 av3 = *(const short8*)(act + m3 * 256 + ((sq ^ (m3 & 31)) << 3)); \
    c00 = MFMA(av0, bv0, c00, 0, 0, 0); c10 = MFMA(av1, bv0, c10, 0, 0, 0);  \
    c20 = MFMA(av2, bv0, c20, 0, 0, 0); c30 = MFMA(av3, bv0, c30, 0, 0, 0);  \
    c01 = MFMA(av0, bv1, c01, 0, 0, 0); c11 = MFMA(av1, bv1, c11, 0, 0, 0);  \
    c21 = MFMA(av2, bv1, c21, 0, 0, 0); c31 = MFMA(av3, bv1, c31, 0, 0, 0);  \
    c02 = MFMA(av0, bv2, c02, 0, 0, 0); c12 = MFMA(av1, bv2, c12, 0, 0, 0);  \
    c22 = MFMA(av2, bv2, c22, 0, 0, 0); c32 = MFMA(av3, bv2, c32, 0, 0, 0);  \
    c03 = MFMA(av0, bv3, c03, 0, 0, 0); c13 = MFMA(av1, bv3, c13, 0, 0, 0);  \
    c23 = MFMA(av2, bv3, c23, 0, 0, 0); c33 = MFMA(av3, bv3, c33, 0, 0, 0);  \
  } while (0)

// one K-step of the 2-col-tile GEMM (layer 4)
#define KSTEP2(sq_) do {                                                     \
    const int sq = (sq_);                                                    \
    short8 bv0 = *(const short8*)(bp0 + sq * 8);                             \
    short8 bv1 = *(const short8*)(bp1 + sq * 8);                             \
    short8 av0 = *(const short8*)(act + m0 * 256 + ((sq ^ (m0 & 31)) << 3)); \
    short8 av1 = *(const short8*)(act + m1 * 256 + ((sq ^ (m1 & 31)) << 3)); \
    short8 av2 = *(const short8*)(act + m2 * 256 + ((sq ^ (m2 & 31)) << 3)); \
    short8 av3 = *(const short8*)(act + m3 * 256 + ((sq ^ (m3 & 31)) << 3)); \
    c00 = MFMA(av0, bv0, c00, 0, 0, 0); c10 = MFMA(av1, bv0, c10, 0, 0, 0);  \
    c20 = MFMA(av2, bv0, c20, 0, 0, 0); c30 = MFMA(av3, bv0, c30, 0, 0, 0);  \
    c01 = MFMA(av0, bv1, c01, 0, 0, 0); c11 = MFMA(av1, bv1, c11, 0, 0, 0);  \
    c21 = MFMA(av2, bv1, c21, 0, 0, 0); c31 = MFMA(av3, bv1, c31, 0, 0, 0);  \
  } while (0)

// store one 16x16 C-tile (named f32x4 CV), row-tile mt, column ng, into swizzled act
#define EPIC(CV, mt, ng, addv) do {                                          \
    int su_ = ((ng) >> 3), so_ = ((ng) & 7);                                 \
    _Pragma("unroll")                                                        \
    for (int r = 0; r < 4; r++) {                                            \
      int mm = (mt) * 16 + quad * 4 + r;                                     \
      act[mm * 256 + ((su_ ^ (mm & 31)) << 3) + so_] =                       \
          f2bf(fmaxf((CV)[r] + (addv), 0.f));                                \
    }                                                                        \
  } while (0)

__global__ void __launch_bounds__(256, 2) nerf_fused(
    const float* __restrict__ rays_o, const float* __restrict__ rays_d,
    const float* __restrict__ t_rand,
    const float* __restrict__ W1, const float* __restrict__ b1,
    const float* __restrict__ b2, const float* __restrict__ b3,
    const float* __restrict__ Wd, const float* __restrict__ bd,
    const float* __restrict__ W4, const float* __restrict__ b4,
    const float* __restrict__ W5, const float* __restrict__ b5,
    const u16* __restrict__ wpack, float* __restrict__ out) {
  __shared__ u16   act[64 * 256];    // 32 KB, XOR-swizzled slots
  __shared__ float zv[64];
  __shared__ float dist[64];
  __shared__ float dens[64];
  __shared__ float rgbL[64 * 4];
  __shared__ float vdirL[4];
  __shared__ float w5L[384];
  __shared__ float b5L[4];

  const int t = threadIdx.x;
  const int lane = t & 63;
  const int wv = t >> 6;        // 0..3
  const int quad = lane >> 4;
  const int l15 = lane & 15;
  const int ray = blockIdx.x;
  const int m0 = l15, m1 = l15 + 16, m2 = l15 + 32, m3 = l15 + 48;

  // ---- setup ----
  if (t < 64) {
    int j = t;
    float fj = (float)j;
    float zj = 0.5f + 2.0f * (fj / 63.0f);
    float lower = (j == 0)  ? zj : 0.5f * (zj + (0.5f + 2.0f * ((fj - 1.0f) / 63.0f)));
    float upper = (j == 63) ? zj : 0.5f * (zj + (0.5f + 2.0f * ((fj + 1.0f) / 63.0f)));
    float tr = t_rand[ray * 64 + j];
    zv[j] = lower + (upper - lower) * tr;
  } else {
    int idx = t - 64;                 // 0..191
    w5L[idx] = W5[idx];
    w5L[idx + 192] = W5[idx + 192];
  }
  if (t < 3) b5L[t] = b5[t];
  if (t == 0) {
    float dx = rays_d[ray * 3 + 0];
    float dy = rays_d[ray * 3 + 1];
    float dz = rays_d[ray * 3 + 2];
    float nrm = sqrtf(dx * dx + dy * dy + dz * dz) + 1e-8f;
    vdirL[0] = dx / nrm; vdirL[1] = dy / nrm; vdirL[2] = dz / nrm;
  }
  __syncthreads();

  if (t < 64) dist[t] = (t < 63) ? (zv[t + 1] - zv[t]) : 1e10f;

  // ---- layer 1: h1 = relu(pts@W1 + b1) -> act (pure vector ops) ----
  {
    int m = t >> 2, p = t & 3;
    float zm = zv[m];
    float px = rays_o[ray * 3 + 0] + rays_d[ray * 3 + 0] * zm;
    float py = rays_o[ray * 3 + 1] + rays_d[ray * 3 + 1] * zm;
    float pz = rays_o[ray * 3 + 2] + rays_d[ray * 3 + 2] * zm;
#pragma unroll
    for (int kk = 0; kk < 64; kk += 8) {
      int k0 = p * 64 + kk;
      f32x4 bva = *(const f32x4*)(b1 + k0);
      f32x4 bvb = *(const f32x4*)(b1 + k0 + 4);
      f32x4 w0a = *(const f32x4*)(W1 + k0);
      f32x4 w0b = *(const f32x4*)(W1 + k0 + 4);
      f32x4 w1a = *(const f32x4*)(W1 + 256 + k0);
      f32x4 w1b = *(const f32x4*)(W1 + 256 + k0 + 4);
      f32x4 w2a = *(const f32x4*)(W1 + 512 + k0);
      f32x4 w2b = *(const f32x4*)(W1 + 512 + k0 + 4);
      f32x4 sa = bva + px * w0a + py * w1a + pz * w2a;
      f32x4 sb = bvb + px * w0b + py * w1b + pz * w2b;
      short8 res;
      res[0] = (short)f2bf(fmaxf(sa[0], 0.f));
      res[1] = (short)f2bf(fmaxf(sa[1], 0.f));
      res[2] = (short)f2bf(fmaxf(sa[2], 0.f));
      res[3] = (short)f2bf(fmaxf(sa[3], 0.f));
      res[4] = (short)f2bf(fmaxf(sb[0], 0.f));
      res[5] = (short)f2bf(fmaxf(sb[1], 0.f));
      res[6] = (short)f2bf(fmaxf(sb[2], 0.f));
      res[7] = (short)f2bf(fmaxf(sb[3], 0.f));
      int u = (k0 >> 3) ^ (m & 31);
      *(short8*)(act + m * 256 + u * 8) = res;
    }
  }
  __syncthreads();

  // ---- layers 2 & 3: h = relu(h@W + b), K=256, N=256, B streamed from L2 ----
#pragma unroll 1
  for (int L = 0; L < 2; L++) {
    const u16* wB = wpack + L * 65536;
    const float* bb = (L == 0) ? b2 : b3;
    const u16* bp0 = wB + (wv * 64 +  0 + l15) * 256;
    const u16* bp1 = wB + (wv * 64 + 16 + l15) * 256;
    const u16* bp2 = wB + (wv * 64 + 32 + l15) * 256;
    const u16* bp3 = wB + (wv * 64 + 48 + l15) * 256;
    f32x4 c00 = ZER4, c01 = ZER4, c02 = ZER4, c03 = ZER4;
    f32x4 c10 = ZER4, c11 = ZER4, c12 = ZER4, c13 = ZER4;
    f32x4 c20 = ZER4, c21 = ZER4, c22 = ZER4, c23 = ZER4;
    f32x4 c30 = ZER4, c31 = ZER4, c32 = ZER4, c33 = ZER4;
#pragma unroll
    for (int kc = 0; kc < 8; kc++) KSTEP4(kc * 4 + quad);
    __syncthreads();               // all act reads done before in-place rewrite
    {
      int ng0 = wv * 64 + l15;
      float bi0 = bb[ng0], bi1 = bb[ng0 + 16], bi2 = bb[ng0 + 32], bi3 = bb[ng0 + 48];
      EPIC(c00, 0, ng0, bi0); EPIC(c10, 1, ng0, bi0);
      EPIC(c20, 2, ng0, bi0); EPIC(c30, 3, ng0, bi0);
      EPIC(c01, 0, ng0 + 16, bi1); EPIC(c11, 1, ng0 + 16, bi1);
      EPIC(c21, 2, ng0 + 16, bi1); EPIC(c31, 3, ng0 + 16, bi1);
      EPIC(c02, 0, ng0 + 32, bi2); EPIC(c12, 1, ng0 + 32, bi2);
      EPIC(c22, 2, ng0 + 32, bi2); EPIC(c32, 3, ng0 + 32, bi2);
      EPIC(c03, 0, ng0 + 48, bi3); EPIC(c13, 1, ng0 + 48, bi3);
      EPIC(c23, 2, ng0 + 48, bi3); EPIC(c33, 3, ng0 + 48, bi3);
    }
    __syncthreads();
  }

  // ---- density: fp32 dot(h3, Wd) ----
  {
    int m = t >> 2, p = t & 3;
    float s = 0.f;
#pragma unroll
    for (int kk = 0; kk < 64; kk += 8) {
      int k0 = p * 64 + kk;
      short8 h = *(const short8*)(act + m * 256 + (((k0 >> 3) ^ (m & 31)) << 3));
      f32x4 wa = *(const f32x4*)(Wd + k0);
      f32x4 wb = *(const f32x4*)(Wd + k0 + 4);
      s += bf2f((u16)h[0]) * wa[0] + bf2f((u16)h[1]) * wa[1]
         + bf2f((u16)h[2]) * wa[2] + bf2f((u16)h[3]) * wa[3]
         + bf2f((u16)h[4]) * wb[0] + bf2f((u16)h[5]) * wb[1]
         + bf2f((u16)h[6]) * wb[2] + bf2f((u16)h[7]) * wb[3];
    }
    s += __shfl_xor(s, 1);
    s += __shfl_xor(s, 2);
    if (p == 0) dens[m] = s + bd[0];
  }

  // ---- layer 4: h4 = relu(h3@W4[:256] + vdir@W4[256:259] + b4), N=128 ----
  {
    const u16* wB = wpack + 131072;
    const u16* bp0 = wB + (wv * 32 +  0 + l15) * 256;
    const u16* bp1 = wB + (wv * 32 + 16 + l15) * 256;
    f32x4 c00 = ZER4, c01 = ZER4;
    f32x4 c10 = ZER4, c11 = ZER4;
    f32x4 c20 = ZER4, c21 = ZER4;
    f32x4 c30 = ZER4, c31 = ZER4;
#pragma unroll
    for (int kc = 0; kc < 8; kc++) KSTEP2(kc * 4 + quad);
    __syncthreads();               // all h3 reads done (incl. density) before rewrite
    {
      float v0 = vdirL[0], v1 = vdirL[1], v2 = vdirL[2];
      int ng0 = wv * 32 + l15;
      float ad0 = b4[ng0] + v0 * W4[32768 + ng0] + v1 * W4[32896 + ng0] + v2 * W4[33024 + ng0];
      int ng1 = ng0 + 16;
      float ad1 = b4[ng1] + v0 * W4[32768 + ng1] + v1 * W4[32896 + ng1] + v2 * W4[33024 + ng1];
      EPIC(c00, 0, ng0, ad0); EPIC(c10, 1, ng0, ad0);
      EPIC(c20, 2, ng0, ad0); EPIC(c30, 3, ng0, ad0);
      EPIC(c01, 0, ng1, ad1); EPIC(c11, 1, ng1, ad1);
      EPIC(c21, 2, ng1, ad1); EPIC(c31, 3, ng1, ad1);
    }
  }
  __syncthreads();

  // ---- rgb = sigmoid(h4@W5 + b5) ----
  {
    int m = t >> 2, p = t & 3;
    float s0 = 0.f, s1 = 0.f, s2 = 0.f;
#pragma unroll
    for (int kk = 0; kk < 32; kk += 8) {
      int k0 = p * 32 + kk;
      short8 h = *(const short8*)(act + m * 256 + (((k0 >> 3) ^ (m & 31)) << 3));
#pragma unroll
      for (int j = 0; j < 8; j++) {
        float hv = bf2f((u16)h[j]);
        int k = k0 + j;
        s0 += hv * w5L[k * 3 + 0];
        s1 += hv * w5L[k * 3 + 1];
        s2 += hv * w5L[k * 3 + 2];
      }
    }
    s0 += __shfl_xor(s0, 1); s0 += __shfl_xor(s0, 2);
    s1 += __shfl_xor(s1, 1); s1 += __shfl_xor(s1, 2);
    s2 += __shfl_xor(s2, 1); s2 += __shfl_xor(s2, 2);
    if (p == 0) {
      rgbL[m * 4 + 0] = 1.f / (1.f + __expf(-(s0 + b5L[0])));
      rgbL[m * 4 + 1] = 1.f / (1.f + __expf(-(s1 + b5L[1])));
      rgbL[m * 4 + 2] = 1.f / (1.f + __expf(-(s2 + b5L[2])));
    }
  }
  __syncthreads();

  // ---- alpha compositing: wave 0 handles the block's single ray ----
  if (t < 64) {
    int j = t;
    float alpha = 1.f - __expf(-fmaxf(dens[j], 0.f) * dist[j]);
    float v = 1.f - alpha + 1e-10f;
    float pscan = v;
#pragma unroll
    for (int d = 1; d < 64; d <<= 1) {
      float o = __shfl_up(pscan, d);
      if (j >= d) pscan *= o;
    }
    float T = __shfl_up(pscan, 1);
    if (j == 0) T = 1.f;
    float w = alpha * T;
    float r0 = w * rgbL[j * 4 + 0];
    float r1 = w * rgbL[j * 4 + 1];
    float r2 = w * rgbL[j * 4 + 2];
    float dp = w * zv[j];
    float ac = w;
#pragma unroll
    for (int d = 32; d; d >>= 1) {
      r0 += __shfl_down(r0, d);
      r1 += __shfl_down(r1, d);
      r2 += __shfl_down(r2, d);
      dp += __shfl_down(dp, d);
      ac += __shfl_down(ac, d);
    }
    if (j == 0) {
      float bg = 1.f - ac;
      out[ray * 3 + 0] = r0 + bg;
      out[ray * 3 + 1] = r1 + bg;
      out[ray * 3 + 2] = r2 + bg;
      out[NRAYS * 3 + ray] = dp;
      out[NRAYS * 4 + ray] = ac;
    }
  }
}

extern "C" void kernel_launch(void* const* d_in, const int* in_sizes, int n_in,
                              void* d_out, int out_size, void* d_ws, size_t ws_size,
                              hipStream_t stream) {
  const float* rays_o = (const float*)d_in[0];
  const float* rays_d = (const float*)d_in[1];
  const float* t_rand = (const float*)d_in[2];
  const float* W1 = (const float*)d_in[3];
  const float* b1 = (const float*)d_in[4];
  const float* W2 = (const float*)d_in[5];
  const float* b2 = (const float*)d_in[6];
  const float* W3 = (const float*)d_in[7];
  const float* b3 = (const float*)d_in[8];
  const float* Wd = (const float*)d_in[9];
  const float* bd = (const float*)d_in[10];
  const float* W4 = (const float*)d_in[11];
  const float* b4 = (const float*)d_in[12];
  const float* W5 = (const float*)d_in[13];
  const float* b5 = (const float*)d_in[14];
  u16* wpack = (u16*)d_ws;
  float* out = (float*)d_out;

  pack_weights<<<640, 256, 0, stream>>>(W2, W3, W4, wpack);
  nerf_fused<<<NRAYS, 256, 0, stream>>>(rays_o, rays_d, t_rand, W1, b1, b2, b3,
                                        Wd, bd, W4, b4, W5, b5, wpack, out);
}